// Round 6
// baseline (181.925 us; speedup 1.0000x reference)
//
#include <hip/hip_runtime.h>
#include <hip/hip_fp16.h>

// ---------------- types ----------------
typedef __attribute__((ext_vector_type(8))) short short8;
typedef __attribute__((ext_vector_type(16))) float f32x16;

#define GLOBAL_AS __attribute__((address_space(1)))
#define LDS_AS __attribute__((address_space(3)))

static __device__ __forceinline__ void gload16(const void* g, void* l) {
    __builtin_amdgcn_global_load_lds((const GLOBAL_AS void*)g, (LDS_AS void*)l, 16, 0, 0);
}

#define SBAR() __builtin_amdgcn_s_barrier()
#define WAITVM(N) asm volatile("s_waitcnt vmcnt(" #N ")" ::: "memory")

// float -> bf16 RNE via bit trick
static __device__ __forceinline__ unsigned short f2bf(float f) {
    union { float f; unsigned u; } v; v.f = f;
    unsigned r = v.u + 0x7FFFu + ((v.u >> 16) & 1u);
    return (unsigned short)(r >> 16);
}

// Detect storage dtype of ortho_vals (round-1 finding: harness delivers fp16
// refs as fp32). Score fp32/fp16/bf16 interpretations of the first 192 values
// against the known outlier range |v| in [1e-5, 0.5]. Deterministic.
static __device__ int detect_vals_kind(const void* vals) {  // 0=f32 1=f16 2=bf16
    const float* f = (const float*)vals;
    const unsigned short* h = (const unsigned short*)vals;
    int s0 = 0, s1 = 0, s2 = 0;
    for (int i = 0; i < 192; ++i) {
        float a0 = fabsf(f[i]);
        if (a0 >= 1e-5f && a0 <= 0.5f) s0++;
        float a1 = fabsf(__half2float(((const __half*)vals)[i]));
        if (a1 >= 1e-5f && a1 <= 0.5f) s1++;
        union { unsigned u; float fv; } c; c.u = ((unsigned)h[i]) << 16;
        float a2 = fabsf(c.fv);
        if (a2 >= 1e-5f && a2 <= 0.5f) s2++;
    }
    if (s0 >= s1 && s0 >= s2) return 0;
    if (s1 >= s2) return 1;
    return 2;
}

// ---------------- kernel 1: fused prep ----------------
// blocks [0,4096): dequant W row -> bf16 (int4 + scale + CSR outliers)
// blocks [4096,6144): x fp32 -> bf16 cast (grid-stride over 2M short8)
__global__ __launch_bounds__(256) void prep_kernel(
    const int* __restrict__ packed,      // [4096][2048] one byte value per int
    const float* __restrict__ scales,    // [4096]
    const void* __restrict__ vals,       // [nnz] dtype auto-detected
    const int* __restrict__ idxs,        // [nnz]
    const int* __restrict__ ptr,         // [4097]
    uint4* __restrict__ Wb4,             // [4096][512] uint4 = 8 bf16
    const float* __restrict__ x,
    unsigned short* __restrict__ xb)
{
    if (blockIdx.x >= 4096) {
        const int n8 = (4096 * 4096) / 8;
        const int stride = 2048 * 256;
        for (int j = (blockIdx.x - 4096) * 256 + threadIdx.x; j < n8; j += stride) {
            const float4 a = ((const float4*)x)[2 * (size_t)j];
            const float4 b = ((const float4*)x)[2 * (size_t)j + 1];
            short8 o;
            o[0] = (short)f2bf(a.x); o[1] = (short)f2bf(a.y);
            o[2] = (short)f2bf(a.z); o[3] = (short)f2bf(a.w);
            o[4] = (short)f2bf(b.x); o[5] = (short)f2bf(b.y);
            o[6] = (short)f2bf(b.z); o[7] = (short)f2bf(b.w);
            *(short8*)(xb + 8 * (size_t)j) = o;
        }
        return;
    }
    __shared__ float sp[4096];
    __shared__ int skind;
    const int row = blockIdx.x;
    float4* sp4 = (float4*)sp;
    const float4 z4 = make_float4(0.f, 0.f, 0.f, 0.f);
    for (int i = threadIdx.x; i < 1024; i += 256) sp4[i] = z4;
    if (threadIdx.x == 0) skind = detect_vals_kind(vals);
    __syncthreads();
    const int kind = skind;
    const int s = ptr[row], e = ptr[row + 1];
    if (kind == 0) {
        const float* vf = (const float*)vals;
        for (int i = s + threadIdx.x; i < e; i += 256) atomicAdd(&sp[idxs[i]], vf[i]);
    } else if (kind == 1) {
        const __half* vh = (const __half*)vals;
        for (int i = s + threadIdx.x; i < e; i += 256) atomicAdd(&sp[idxs[i]], __half2float(vh[i]));
    } else {
        const unsigned short* vb = (const unsigned short*)vals;
        for (int i = s + threadIdx.x; i < e; i += 256) {
            union { unsigned u; float fv; } c; c.u = ((unsigned)vb[i]) << 16;
            atomicAdd(&sp[idxs[i]], c.fv);
        }
    }
    __syncthreads();
    const float sc = scales[row];
    const int4* prow4 = (const int4*)(packed + (size_t)row * 2048);
    uint4* wrow4 = Wb4 + (size_t)row * 512;
    for (int j = threadIdx.x; j < 512; j += 256) {
        const int4 p = prow4[j];
        const float* spc = sp + 8 * j;
        uint4 o;
        o.x = (unsigned)f2bf((float)((p.x & 0xF) - 8) * sc + spc[0]) |
              ((unsigned)f2bf((float)(((p.x >> 4) & 0xF) - 8) * sc + spc[1]) << 16);
        o.y = (unsigned)f2bf((float)((p.y & 0xF) - 8) * sc + spc[2]) |
              ((unsigned)f2bf((float)(((p.y >> 4) & 0xF) - 8) * sc + spc[3]) << 16);
        o.z = (unsigned)f2bf((float)((p.z & 0xF) - 8) * sc + spc[4]) |
              ((unsigned)f2bf((float)(((p.z >> 4) & 0xF) - 8) * sc + spc[5]) << 16);
        o.w = (unsigned)f2bf((float)((p.w & 0xF) - 8) * sc + spc[6]) |
              ((unsigned)f2bf((float)(((p.w >> 4) & 0xF) - 8) * sc + spc[7]) << 16);
        wrow4[j] = o;
    }
}

// ---------------- kernel 2: 256x256-tile pipelined bf16 GEMM, 32x32x16 MFMA ----------------
// Round-6 change vs round-5 (schedule preserved): MFMA shape 16x16x32 ->
// 32x32x16 (measured 2495 vs 2075 TF ceiling, half the issue slots), with the
// row-XOR swizzle extended to f(row) = (row ^ (row>>3)) & 7 on BOTH the
// pre-swizzled global staging source and the fragment reads, so 32-row
// fragment reads stay bank-conflict-free (every aligned 8-lane beat spans all
// 8 segments). Per wave: 4Mx2N tiles of 32x32, acc = 4x2 f32x16 (128 regs).
__global__ __launch_bounds__(512, 2) void gemm_bt_kernel(
    const unsigned short* __restrict__ A,   // bf16 bits, M x K
    const unsigned short* __restrict__ B,   // bf16 bits, N x K
    float* __restrict__ C)                  // fp32, M x N
{
    constexpr int K = 4096;
    constexpr int N = 4096;
    __shared__ __attribute__((aligned(128))) char smem[131072]; // [2 buf][A 32KB | B 32KB]

    const int tid = threadIdx.x;
    const int lane = tid & 63;
    const int wv = tid >> 6;              // 0..7
    const int bid = (blockIdx.x & 7) * 32 + (blockIdx.x >> 3);  // bijective XCD swizzle
    const int bm = bid >> 4;              // 16 M-tiles
    const int bn = bid & 15;              // 16 N-tiles

    // ---- staging: one gload16 round (512 thr x 16B) = 64 rows x 128B ----
    const int grow = tid >> 3;                                  // row within round
    const int sg = (tid & 7) ^ ((grow ^ (grow >> 3)) & 7);      // pre-swizzle: f(row)
    const unsigned short* ag = A + (size_t)(bm * 256 + grow) * K + sg * 8;
    const unsigned short* bg = B + (size_t)(bn * 256 + grow) * K + sg * 8;
    char* ldsw = smem + (wv * 8) * 128;                         // wave-uniform base

#define STAGE(R, KT, BUF)                                                              \
    {                                                                                  \
        if ((R) < 4)                                                                   \
            gload16(ag + (size_t)((R) * 64) * K + (KT),                                \
                    ldsw + (BUF) * 65536 + (R) * 64 * 128);                            \
        else                                                                           \
            gload16(bg + (size_t)(((R) - 4) * 64) * K + (KT),                          \
                    ldsw + (BUF) * 65536 + 32768 + ((R) - 4) * 64 * 128);              \
    }

    // ---- fragment geometry (32x32x16): lane holds row/col (lane&31), k-half (lane>>5) ----
    const int wr = wv >> 2, wc = wv & 3;                // 2x4 wave grid
    const int l31 = lane & 31;
    const int lhi = lane >> 5;                          // k-half: bytes lhi*16 within 32B k-step
    const int rowa = wr * 128 + l31;                    // + mt*32
    const int rowb = wc * 64 + l31;                     // + nt*32
    // seg_final = (ks*2 + lhi) ^ f(row);  f(row) = (row ^ (row>>3)) & 7
    int fa[4], fb[2];
#pragma unroll
    for (int mt = 0; mt < 4; ++mt) {
        const int r = rowa + mt * 32;
        fa[mt] = (r ^ (r >> 3)) & 7;
    }
#pragma unroll
    for (int nt = 0; nt < 2; ++nt) {
        const int r = rowb + nt * 32;
        fb[nt] = (r ^ (r >> 3)) & 7;
    }

#define LDA4(DST, KS, BUF)                                                             \
    {                                                                                  \
        _Pragma("unroll") for (int mt = 0; mt < 4; ++mt) {                             \
            const int row_ = rowa + mt * 32;                                           \
            const int seg_ = (((KS) * 2 + lhi) ^ fa[mt]);                              \
            DST[mt] = *(const short8*)(smem + (BUF) * 65536 + row_ * 128 + seg_ * 16); \
        }                                                                              \
    }
#define LDB2(DST, KS, BUF)                                                             \
    {                                                                                  \
        _Pragma("unroll") for (int nt = 0; nt < 2; ++nt) {                             \
            const int row_ = rowb + nt * 32;                                           \
            const int seg_ = (((KS) * 2 + lhi) ^ fb[nt]);                              \
            DST[nt] = *(const short8*)(smem + (BUF) * 65536 + 32768 + row_ * 128 +     \
                                       seg_ * 16);                                     \
        }                                                                              \
    }
#define MFMA8(AF, BF)                                                                  \
    {                                                                                  \
        __builtin_amdgcn_s_setprio(1);                                                 \
        _Pragma("unroll") for (int mt = 0; mt < 4; ++mt)                               \
            _Pragma("unroll") for (int nt = 0; nt < 2; ++nt)                           \
                acc[mt][nt] = __builtin_amdgcn_mfma_f32_32x32x16_bf16(                 \
                    AF[mt], BF[nt], acc[mt][nt], 0, 0, 0);                             \
        __builtin_amdgcn_s_setprio(0);                                                 \
    }

    f32x16 acc[4][2];
#pragma unroll
    for (int mt = 0; mt < 4; ++mt)
#pragma unroll
        for (int nt = 0; nt < 2; ++nt) acc[mt][nt] = (f32x16)0.0f;

    // ---- prologue: stage tile 0 into buf0 ----
#pragma unroll
    for (int r = 0; r < 8; ++r) STAGE(r, 0, 0);

    constexpr int NT = K / 64;   // 64 K-tiles
    for (int t = 0; t < NT; ++t) {
        const int cur = t & 1, nxt = cur ^ 1;
        const int ktn = (t + 1) * 64;
        __builtin_amdgcn_sched_barrier(0);
        // vmcnt(2): waits all of tile t (8 rounds), leaves the 2 fresh t+1 loads.
        if (t + 1 < NT) {
            STAGE(0, ktn, nxt); STAGE(1, ktn, nxt);
            WAITVM(2);
        } else {
            WAITVM(0);
        }
        SBAR();

        // ---- free-running region: 24 ds_read + 32 MFMA + 6 staged loads ----
        short8 af0[4], af1[4], bf0[2], bf1[2];
        LDA4(af0, 0, cur); LDB2(bf0, 0, cur);
        if (t + 1 < NT) { STAGE(2, ktn, nxt); STAGE(3, ktn, nxt); }
        MFMA8(af0, bf0);
        LDA4(af1, 1, cur); LDB2(bf1, 1, cur);
        if (t + 1 < NT) { STAGE(4, ktn, nxt); STAGE(5, ktn, nxt); }
        MFMA8(af1, bf1);
        LDA4(af0, 2, cur); LDB2(bf0, 2, cur);
        if (t + 1 < NT) { STAGE(6, ktn, nxt); STAGE(7, ktn, nxt); }
        MFMA8(af0, bf0);
        LDA4(af1, 3, cur); LDB2(bf1, 3, cur);
        MFMA8(af1, bf1);
        SBAR();   // all waves done reading buf[cur]
    }

    // ---- epilogue: 32x32 C/D layout col=lane&31, row=(reg&3)+8*(reg>>2)+4*(lane>>5) ----
    const int crow0 = bm * 256 + wr * 128 + 4 * lhi;
    const int ccol0 = bn * 256 + wc * 64 + l31;
#pragma unroll
    for (int mt = 0; mt < 4; ++mt)
#pragma unroll
        for (int nt = 0; nt < 2; ++nt)
#pragma unroll
            for (int reg = 0; reg < 16; ++reg) {
                const int row_ = crow0 + mt * 32 + (reg & 3) + 8 * (reg >> 2);
                C[(size_t)row_ * N + ccol0 + nt * 32] = acc[mt][nt][reg];
            }
}

// ---------------- launch ----------------
extern "C" void kernel_launch(void* const* d_in, const int* in_sizes, int n_in,
                              void* d_out, int out_size, void* d_ws, size_t ws_size,
                              hipStream_t stream) {
    const float* x        = (const float*)d_in[0];
    const int* packed     = (const int*)d_in[1];
    const float* scales   = (const float*)d_in[2];
    const void* vals      = (const void*)d_in[3];
    const int* idxs       = (const int*)d_in[4];
    const int* ptr        = (const int*)d_in[5];
    float* out            = (float*)d_out;

    unsigned short* Wb = (unsigned short*)d_ws;            // 4096*4096 bf16 = 32 MB
    unsigned short* Xb = Wb + (size_t)4096 * 4096;         // next 32 MB

    prep_kernel<<<6144, 256, 0, stream>>>(packed, scales, vals, idxs, ptr,
                                          (uint4*)Wb, x, Xb);
    gemm_bt_kernel<<<256, 512, 0, stream>>>(Xb, Wb, out);
}